// Round 1
// baseline (422.368 us; speedup 1.0000x reference)
//
#include <hip/hip_runtime.h>

// Bilinear spatial-transformer sampling.
// image: [B=32, H=256, W=256, C=32] f32 (NHWC), theta: [B,6] f32
// out:   [B, 256, 256, 32] f32
//
// Mapping: 1 thread = 1 float4 channel-group (C/4 = 8 groups) of 1 output
// pixel. 8 consecutive lanes cover one pixel's 32 channels -> each corner
// gather is a 128B contiguous segment per pixel; store is fully coalesced.

#define OUT_H 256
#define OUT_W 256
#define IMG_H 256
#define IMG_W 256
#define NCH   32
#define NB    32

__global__ __launch_bounds__(256) void stn_bilinear_kernel(
    const float* __restrict__ img,
    const float* __restrict__ theta,
    float* __restrict__ out)
{
    int idx = blockIdx.x * 256 + threadIdx.x;      // [0, B*Ho*Wo*8)
    int cg  = idx & 7;                              // channel group (float4)
    int p   = idx >> 3;                             // pixel index
    int wo  = p & (OUT_W - 1);
    int ho  = (p >> 8) & (OUT_H - 1);
    int b   = p >> 16;

    // theta broadcast (uniform per batch; L1/scalar-cached)
    const float* t = theta + b * 6;
    float t0 = t[0], t1 = t[1], t2 = t[2], t3 = t[3], t4 = t[4], t5 = t[5];

    // regular grid in [-1,1]: linspace(-1,1,256) -> step 2/255
    const float step = 2.0f / 255.0f;
    float xn = fmaf((float)wo, step, -1.0f);
    float yn = fmaf((float)ho, step, -1.0f);

    // affine transform
    float sx = t0 * xn + t1 * yn + t2;
    float sy = t3 * xn + t4 * yn + t5;

    // [-1,1] -> pixel coords (scale by W, not W-1, matching reference)
    float x = 0.5f * (sx + 1.0f) * (float)IMG_W;
    float y = 0.5f * (sy + 1.0f) * (float)IMG_H;

    // corner indices: truncation toward zero (matches astype(int32)), then clip
    int x0 = (int)x;
    int y0 = (int)y;
    int x1 = x0 + 1;
    int y1 = y0 + 1;
    x0 = min(max(x0, 0), IMG_W - 1);
    x1 = min(max(x1, 0), IMG_W - 1);
    y0 = min(max(y0, 0), IMG_H - 1);
    y1 = min(max(y1, 0), IMG_H - 1);

    // bilinear weights from CLIPPED corner coords (matches reference)
    float x0f = (float)x0, x1f = (float)x1;
    float y0f = (float)y0, y1f = (float)y1;
    float wa = (x1f - x) * (y1f - y);
    float wb = (x1f - x) * (y - y0f);
    float wc = (x - x0f) * (y1f - y);
    float wd = (x - x0f) * (y - y0f);

    // gather 4 corners as float4 (channel-group cg)
    const float4* imgv = (const float4*)img;
    size_t b_off = (size_t)b * (IMG_H * IMG_W * (NCH / 4));   // float4 units
    size_t r0 = b_off + (size_t)(y0 * IMG_W) * (NCH / 4);
    size_t r1 = b_off + (size_t)(y1 * IMG_W) * (NCH / 4);
    float4 pa = imgv[r0 + (size_t)x0 * (NCH / 4) + cg];
    float4 pb = imgv[r1 + (size_t)x0 * (NCH / 4) + cg];
    float4 pc = imgv[r0 + (size_t)x1 * (NCH / 4) + cg];
    float4 pd = imgv[r1 + (size_t)x1 * (NCH / 4) + cg];

    float4 o;
    o.x = wa * pa.x + wb * pb.x + wc * pc.x + wd * pd.x;
    o.y = wa * pa.y + wb * pb.y + wc * pc.y + wd * pd.y;
    o.z = wa * pa.z + wb * pb.z + wc * pc.z + wd * pd.z;
    o.w = wa * pa.w + wb * pb.w + wc * pc.w + wd * pd.w;

    ((float4*)out)[idx] = o;
}

extern "C" void kernel_launch(void* const* d_in, const int* in_sizes, int n_in,
                              void* d_out, int out_size, void* d_ws, size_t ws_size,
                              hipStream_t stream)
{
    const float* img   = (const float*)d_in[0];
    const float* theta = (const float*)d_in[1];
    float* out = (float*)d_out;

    // total threads = B*Ho*Wo*(C/4) = 32*256*256*8 = 16,777,216
    int total = NB * OUT_H * OUT_W * (NCH / 4);
    int blocks = total / 256;
    stn_bilinear_kernel<<<blocks, 256, 0, stream>>>(img, theta, out);
}